// Round 3
// baseline (538.282 us; speedup 1.0000x reference)
//
#include <hip/hip_runtime.h>
#include <float.h>
#include <stdint.h>

#define D_DIM 784
#define KPADB 832           // 13 x 64 bytes (i8 per row)
#define N_TRAIN 50000
#define NPAD 50048
#define B_TEST 2048
#define N_CLASSES 10
#define TOPK 5
#define NBLK 391            // ceil(50048/128)
#define SEL 16              // exact-rescore candidate count per row (i8 needs margin)
#define SBIAS 12645136      // 784 * 127^2: makes integer score non-negative

typedef __attribute__((ext_vector_type(4))) int int4v;

__device__ inline unsigned umax32(unsigned a, unsigned b) { return a > b ? a : b; }

// branchless sorted-insert (desc) of u64 into SEL-deep list
__device__ inline void insS(unsigned long long* tk, unsigned long long v) {
    #pragma unroll
    for (int s = 0; s < SEL; ++s) {
        unsigned long long mx = v > tk[s] ? v : tk[s];
        unsigned long long mn = v > tk[s] ? tk[s] : v;
        tk[s] = mx; v = mn;
    }
}

// branchless sorted-insert (desc) of u32 into 5-deep list
__device__ inline void ins5u(unsigned* tk, unsigned v) {
    #pragma unroll
    for (int s = 0; s < TOPK; ++s) {
        unsigned mx = v > tk[s] ? v : tk[s];
        unsigned mn = v > tk[s] ? tk[s] : v;
        tk[s] = mx; v = mn;
    }
}

// float pair-insert for fallback path
#define INSERT5(tvarr, tiarr, CV, CI)                                   \
    {                                                                   \
        float _cv = (CV); int _ci = (CI);                               \
        _Pragma("unroll")                                               \
        for (int _s = 0; _s < TOPK; ++_s) {                             \
            bool _bet = (_cv > tvarr[_s]) ||                            \
                        (_cv == tvarr[_s] && _ci < tiarr[_s]);          \
            float _fv = _bet ? tvarr[_s] : _cv;                         \
            int   _fi = _bet ? tiarr[_s] : _ci;                         \
            tvarr[_s] = _bet ? _cv : tvarr[_s];                         \
            tiarr[_s] = _bet ? _ci : tiarr[_s];                         \
            _cv = _fv; _ci = _fi;                                       \
        }                                                               \
    }

// pack 4 floats -> 4 x i8 (q = round(254*x - 127), symmetric centered quant)
__device__ inline unsigned pack4q(float4 f) {
    int q0 = __float2int_rn(fmaf(f.x, 254.f, -127.f));
    int q1 = __float2int_rn(fmaf(f.y, 254.f, -127.f));
    int q2 = __float2int_rn(fmaf(f.z, 254.f, -127.f));
    int q3 = __float2int_rn(fmaf(f.w, 254.f, -127.f));
    return (unsigned)(q0 & 255) | ((unsigned)(q1 & 255) << 8) |
           ((unsigned)(q2 & 255) << 16) | ((unsigned)(q3 & 255) << 24);
}

// ---------- quantize fp32 -> i8 (centered), both tensors, one launch ----------
// one wave per row; lane covers 16 elements (16 bytes out). K-pad bytes = 0
// (q=0 means u=0 -> contributes nothing to the centered dot product).
__global__ __launch_bounds__(256)
void quant_kernel(const float* __restrict__ xtr, const float* __restrict__ xte,
                  char* __restrict__ Bq, char* __restrict__ Aq) {
    const int blk = blockIdx.x;
    const float* src;
    char* dst;
    int rows_src, row;
    if (blk < NPAD / 4) {
        src = xtr; dst = Bq; rows_src = N_TRAIN;
        row = blk * 4 + (threadIdx.x >> 6);
    } else {
        src = xte; dst = Aq; rows_src = B_TEST;
        row = (blk - NPAD / 4) * 4 + (threadIdx.x >> 6);
        if (row >= B_TEST) return;
    }
    const int lane = threadIdx.x & 63;
    if (lane >= 52) return;                       // 52*16 = 832 bytes per row
    uint4 w = {0u, 0u, 0u, 0u};
    if (row < rows_src && lane < 49) {            // 49*16 = 784 real elements
        const float4* p = (const float4*)(src + (size_t)row * D_DIM + lane * 16);
        w.x = pack4q(p[0]);
        w.y = pack4q(p[1]);
        w.z = pack4q(p[2]);
        w.w = pack4q(p[3]);
    }
    *(uint4*)(dst + (size_t)row * KPADB + lane * 16) = w;
}

// ---------------- i8 MFMA GEMM + packed-u32 top-5 epilogue ----------------
// Same verified structure as the f16 round-2 kernel, halved in every dimension:
// per K-tile (64 i8): 4 G2L/thread, 8 ds_read_b128/wave, 16 mfma_i32_16x16x64_i8.
// Score = sum(qa*qb) is the exact integer rank key (rowsum cancels for centered
// quant); key = ((s + SBIAS) << 7) | col is lossless (25+7 = 32 bits).
__global__ __launch_bounds__(256, 4)
void knn_mfma(const char* __restrict__ Aq, const char* __restrict__ Bq,
              unsigned* __restrict__ cval) {
    const int bid = blockIdx.x;
    const int xcd = bid & 7;
    const int sidx = bid >> 3;
    const int st_g = (sidx >> 4) * 8 + xcd;
    const int r16 = sidx & 15;
    const int mblk = (st_g & 3) * 4 + (r16 & 3);
    const int nchunk = (st_g >> 2) * 4 + (r16 >> 2);
    if (nchunk >= NBLK) return;

    __shared__ char lds_raw[39936] __attribute__((aligned(16)));
    // stage: A tile 8KB at +0, B tile 8KB at +8192 (only 16KB used for staging)
    unsigned* epi  = (unsigned*)lds_raw;             // [128 cols][68] u32
    unsigned* lval = (unsigned*)(lds_raw + 34816);   // [64][4][5] u32

    const int tid = threadIdx.x;
    const int w = tid >> 6, lane = tid & 63;
    const int l15 = lane & 15, q = lane >> 4;
    const int mb = mblk * 128, nb = nchunk * 128;
    const int mw = (w & 1) * 64, nw = (w >> 1) * 64;

    // staging: wave w loads half-tile: tile = w>>1 (0=A,1=B), half = w&1
    const int s_tile = w >> 1, s_half = w & 1;
    const char* sbase = (s_tile == 0) ? (Aq + (size_t)mb * KPADB)
                                      : (Bq + (size_t)nb * KPADB);
    const char* srow = sbase + (size_t)s_half * 64 * KPADB;
    char* ldsw = lds_raw + s_tile * 8192 + s_half * 4096;

    // pre-swizzled global source offsets (4 chunks of 16B per 64B row-tile)
    int choff[4];
    #pragma unroll
    for (int c = 0; c < 4; ++c) {
        int s = c * 64 + lane;               // 16B-chunk index in half-tile
        int rl = s >> 2;                     // row-in-half 0..63
        int k4 = (s & 3) ^ (rl & 3);         // swizzled chunk
        choff[c] = rl * KPADB + k4 * 16;
    }
    // swizzled ds_read byte offsets; row&3 == l15&3 for all fragment rows
    const int ch = (q ^ (l15 & 3)) * 16;
    int aoff[4], boff[4];
    #pragma unroll
    for (int i = 0; i < 4; ++i) {
        aoff[i] = (mw + i * 16 + l15) * 64 + ch;
        boff[i] = (nw + i * 16 + l15) * 64 + ch;
    }

    int4v acc[4][4];
    #pragma unroll
    for (int i = 0; i < 4; ++i)
        #pragma unroll
        for (int j = 0; j < 4; ++j)
            acc[i][j] = (int4v){0, 0, 0, 0};

    for (int kt = 0; kt < KPADB; kt += 64) {
        #pragma unroll
        for (int c = 0; c < 4; ++c) {
            __builtin_amdgcn_global_load_lds(
                (const __attribute__((address_space(1))) void*)(srow + choff[c] + kt),
                (__attribute__((address_space(3))) void*)(ldsw + c * 1024),
                16, 0, 0);
        }
        __syncthreads();
        {
            int4v a[4], b[4];
            #pragma unroll
            for (int i = 0; i < 4; ++i) a[i] = *(const int4v*)(lds_raw + aoff[i]);
            #pragma unroll
            for (int j = 0; j < 4; ++j) b[j] = *(const int4v*)(lds_raw + 8192 + boff[j]);
            #pragma unroll
            for (int i = 0; i < 4; ++i)
                #pragma unroll
                for (int j = 0; j < 4; ++j)
                    acc[i][j] = __builtin_amdgcn_mfma_i32_16x16x64_i8(a[i], b[j], acc[i][j], 0, 0, 0);
        }
        __syncthreads();
    }

    // ---- epilogue: packed keys + branch-free top-5 per (row, chunk) ----
    int okn[4];
    #pragma unroll
    for (int j = 0; j < 4; ++j) okn[j] = (nb + nw + j * 16 + l15 < N_TRAIN);

    for (int h = 0; h < 2; ++h) {
        __syncthreads();
        if ((w & 1) == h) {
            #pragma unroll
            for (int i = 0; i < 4; ++i) {
                int r = i * 16 + q * 4;
                #pragma unroll
                for (int j = 0; j < 4; ++j) {
                    int col = nw + j * 16 + l15;
                    uint4 kv;
                    if (okn[j]) {
                        int4v s = acc[i][j];
                        kv.x = ((unsigned)(s.x + SBIAS) << 7) | (unsigned)col;
                        kv.y = ((unsigned)(s.y + SBIAS) << 7) | (unsigned)col;
                        kv.z = ((unsigned)(s.z + SBIAS) << 7) | (unsigned)col;
                        kv.w = ((unsigned)(s.w + SBIAS) << 7) | (unsigned)col;
                    } else {
                        kv.x = kv.y = kv.z = kv.w = (unsigned)col;
                    }
                    *(uint4*)(epi + col * 68 + r) = kv;
                }
            }
        }
        __syncthreads();
        // scan: thread t -> row (t&63), col-quarter (t>>6); branch-free extraction
        {
            int r = tid & 63, qq = tid >> 6;
            const unsigned* ebase = epi + (qq * 32) * 68 + r;
            unsigned k[32];
            #pragma unroll
            for (int c = 0; c < 32; ++c) k[c] = ebase[c * 68];
            unsigned m5[TOPK];
            #pragma unroll
            for (int rnd = 0; rnd < TOPK; ++rnd) {
                unsigned t16[16];
                #pragma unroll
                for (int c = 0; c < 16; ++c) t16[c] = umax32(k[2*c], k[2*c+1]);
                #pragma unroll
                for (int c = 0; c < 8; ++c) t16[c] = umax32(t16[2*c], t16[2*c+1]);
                #pragma unroll
                for (int c = 0; c < 4; ++c) t16[c] = umax32(t16[2*c], t16[2*c+1]);
                unsigned m = umax32(umax32(t16[0], t16[1]), umax32(t16[2], t16[3]));
                m5[rnd] = m;
                if (rnd < TOPK - 1) {
                    #pragma unroll
                    for (int c = 0; c < 32; ++c) k[c] = (k[c] == m) ? 0u : k[c];
                }
            }
            #pragma unroll
            for (int s = 0; s < TOPK; ++s) lval[(r * 4 + qq) * TOPK + s] = m5[s];
        }
        __syncthreads();
        if (tid < 64) {
            unsigned tv[TOPK] = {0u, 0u, 0u, 0u, 0u};
            for (int qq = 0; qq < 4; ++qq)
                #pragma unroll
                for (int s = 0; s < TOPK; ++s) {
                    unsigned cv = lval[(tid * 4 + qq) * TOPK + s];
                    if (cv > tv[TOPK - 1]) ins5u(tv, cv);
                }
            int grow = mb + h * 64 + tid;
            size_t base = ((size_t)grow * NBLK + nchunk) * TOPK;
            #pragma unroll
            for (int s = 0; s < TOPK; ++s) cval[base + s] = tv[s];
        }
    }
}

// ------- merge packed candidates -> top-16, exact fp64 rescore, vote -------
__global__ __launch_bounds__(256)
void knn_final(const unsigned* __restrict__ cval,
               const float* __restrict__ xt, const float* __restrict__ xtr,
               const int* __restrict__ y, int* __restrict__ out) {
    __shared__ unsigned long long sv[256][SEL];   // 32 KB
    __shared__ double cs[SEL];
    __shared__ int    cn[SEL];
    const int b = blockIdx.x;
    const int t = threadIdx.x;

    unsigned long long tk[SEL];
    #pragma unroll
    for (int s = 0; s < SEL; ++s) tk[s] = 0ull;

    const unsigned* row = cval + (size_t)b * (NBLK * TOPK);
    for (int e = t; e < NBLK * TOPK; e += 256) {
        unsigned v = row[e];
        int chunk = e / TOPK;                       // magic-mul
        unsigned n = (unsigned)chunk * 128u + (v & 127u);
        unsigned long long v64 = ((unsigned long long)v << 16) | n;
        if (v64 > tk[SEL - 1]) insS(tk, v64);
    }
    #pragma unroll
    for (int s = 0; s < SEL; ++s) sv[t][s] = tk[s];
    __syncthreads();

    for (int off = 128; off >= 1; off >>= 1) {
        if (t < off) {
            if (sv[t + off][0] > tk[SEL - 1]) {
                #pragma unroll
                for (int s = 0; s < SEL; ++s) {
                    unsigned long long v = sv[t + off][s];
                    if (v > tk[SEL - 1]) insS(tk, v);
                }
                #pragma unroll
                for (int s = 0; s < SEL; ++s) sv[t][s] = tk[s];
            }
        }
        __syncthreads();
    }

    // exact fp64 rescore: candidate c handled by quarter-wave (16 lanes)
    const int c = t >> 4, ql = t & 15;
    {
        int n = (int)(sv[0][c] & 0xFFFFull);
        double dot = 0.0, rs = 0.0;
        if (n < N_TRAIN) {
            const float4* pa = (const float4*)(xt + (size_t)b * D_DIM);
            const float4* pb = (const float4*)(xtr + (size_t)n * D_DIM);
            #pragma unroll
            for (int jj = 0; jj < 13; ++jj) {
                int j = ql + jj * 16;
                if (j < 196) {
                    float4 a = pa[j], bb = pb[j];
                    dot += (double)a.x * bb.x + (double)a.y * bb.y +
                           (double)a.z * bb.z + (double)a.w * bb.w;
                    rs  += (double)bb.x + (double)bb.y + (double)bb.z + (double)bb.w;
                }
            }
        }
        #pragma unroll
        for (int off = 8; off > 0; off >>= 1) {
            dot += __shfl_down(dot, off, 16);
            rs  += __shfl_down(rs, off, 16);
        }
        if (ql == 0) {
            cs[c] = (n < N_TRAIN) ? (2.0 * dot - rs) : -1.0e300;
            cn[c] = n;
        }
    }
    __syncthreads();

    if (t == 0) {
        double bv[TOPK]; int bi[TOPK];
        #pragma unroll
        for (int s = 0; s < TOPK; ++s) { bv[s] = -1.0e300; bi[s] = 0x7fffffff; }
        for (int cc = 0; cc < SEL; ++cc) {
            double cv = cs[cc]; int ci = cn[cc];
            #pragma unroll
            for (int s = 0; s < TOPK; ++s) {
                bool bet = (cv > bv[s]) || (cv == bv[s] && ci < bi[s]);
                double fv = bet ? bv[s] : cv;
                int    fi = bet ? bi[s] : ci;
                bv[s] = bet ? cv : bv[s];
                bi[s] = bet ? ci : bi[s];
                cv = fv; ci = fi;
            }
        }
        int lab[TOPK];
        #pragma unroll
        for (int s = 0; s < TOPK; ++s) lab[s] = y[bi[s]];
        int best_c = 0, best_cnt = -1;
        #pragma unroll
        for (int cc = 0; cc < N_CLASSES; ++cc) {
            int cnt = 0;
            #pragma unroll
            for (int s = 0; s < TOPK; ++s) cnt += (lab[s] == cc) ? 1 : 0;
            if (cnt > best_cnt) { best_cnt = cnt; best_c = cc; }
        }
        out[b] = best_c;
    }
}

// ================= fallback (round-1 fp32 path, known-correct) =================
#define FBM 64
#define FBN 64
#define FBK 16
#define FNCH 32
#define FCHUNK 1600

__global__ __launch_bounds__(256)
void rowsum_kernel(const float* __restrict__ x, float* __restrict__ s) {
    int row = blockIdx.x * 4 + (threadIdx.x >> 6);
    int lane = threadIdx.x & 63;
    if (row >= N_TRAIN) return;
    const float* p = x + (size_t)row * D_DIM;
    float acc = 0.f;
    for (int i = lane; i < D_DIM; i += 64) acc += p[i];
    #pragma unroll
    for (int off = 32; off > 0; off >>= 1) acc += __shfl_down(acc, off, 64);
    if (lane == 0) s[row] = acc;
}

__global__ __launch_bounds__(256)
void knn_phaseA_fb(const float* __restrict__ xt, const float* __restrict__ xtr,
                   const float* __restrict__ strain,
                   float* __restrict__ cval, int* __restrict__ cidx) {
    __shared__ float As[FBK][FBM + 4];
    __shared__ float Bs[FBK][FBN + 4];
    __shared__ float lv[FBM][16][TOPK];
    __shared__ int   li[FBM][16][TOPK];

    const int tid = threadIdx.x;
    const int tx = tid & 15, ty = tid >> 4;
    const int b0 = blockIdx.x * FBM;
    const int chunk = blockIdx.y;
    const int n_base = chunk * FCHUNK;
    const int lrow = tid >> 2;
    const int lk4  = (tid & 3) * 4;

    float tv[4][TOPK]; int ti[4][TOPK];
    #pragma unroll
    for (int i = 0; i < 4; ++i)
        #pragma unroll
        for (int s = 0; s < TOPK; ++s) { tv[i][s] = -FLT_MAX; ti[i][s] = 0x7fffffff; }

    for (int nt = 0; nt < FCHUNK; nt += FBN) {
        const int n0 = n_base + nt;
        double accd[4][4];
        #pragma unroll
        for (int i = 0; i < 4; ++i)
            #pragma unroll
            for (int j = 0; j < 4; ++j) accd[i][j] = 0.0;

        for (int kt = 0; kt < D_DIM; kt += FBK) {
            float4 av = *(const float4*)(xt + (size_t)(b0 + lrow) * D_DIM + kt + lk4);
            As[lk4 + 0][lrow] = av.x; As[lk4 + 1][lrow] = av.y;
            As[lk4 + 2][lrow] = av.z; As[lk4 + 3][lrow] = av.w;
            int nr = n0 + lrow;
            float4 bv = make_float4(0.f, 0.f, 0.f, 0.f);
            if (nr < N_TRAIN) bv = *(const float4*)(xtr + (size_t)nr * D_DIM + kt + lk4);
            Bs[lk4 + 0][lrow] = bv.x; Bs[lk4 + 1][lrow] = bv.y;
            Bs[lk4 + 2][lrow] = bv.z; Bs[lk4 + 3][lrow] = bv.w;
            __syncthreads();

            float accf[4][4] = {{0.f}};
            #pragma unroll
            for (int k = 0; k < FBK; ++k) {
                float a[4], b[4];
                #pragma unroll
                for (int i = 0; i < 4; ++i) a[i] = As[k][ty * 4 + i];
                #pragma unroll
                for (int j = 0; j < 4; ++j) b[j] = Bs[k][tx * 4 + j];
                #pragma unroll
                for (int i = 0; i < 4; ++i)
                    #pragma unroll
                    for (int j = 0; j < 4; ++j) accf[i][j] += a[i] * b[j];
            }
            #pragma unroll
            for (int i = 0; i < 4; ++i)
                #pragma unroll
                for (int j = 0; j < 4; ++j) accd[i][j] += (double)accf[i][j];
            __syncthreads();
        }

        #pragma unroll
        for (int j = 0; j < 4; ++j) {
            int n = n0 + tx * 4 + j;
            if (n < N_TRAIN) {
                float sn = strain[n];
                #pragma unroll
                for (int i = 0; i < 4; ++i) {
                    float sc = (float)(2.0 * accd[i][j] - (double)sn);
                    if (sc > tv[i][TOPK - 1] ||
                        (sc == tv[i][TOPK - 1] && n < ti[i][TOPK - 1])) {
                        INSERT5(tv[i], ti[i], sc, n);
                    }
                }
            }
        }
    }

    #pragma unroll
    for (int i = 0; i < 4; ++i)
        #pragma unroll
        for (int s = 0; s < TOPK; ++s) {
            lv[ty * 4 + i][tx][s] = tv[i][s];
            li[ty * 4 + i][tx][s] = ti[i][s];
        }
    __syncthreads();

    if (tid < FBM) {
        float bv5[TOPK]; int bi5[TOPK];
        #pragma unroll
        for (int s = 0; s < TOPK; ++s) { bv5[s] = -FLT_MAX; bi5[s] = 0x7fffffff; }
        for (int tt = 0; tt < 16; ++tt)
            #pragma unroll
            for (int s = 0; s < TOPK; ++s) {
                float cv = lv[tid][tt][s]; int ci = li[tid][tt][s];
                if (cv > bv5[TOPK - 1] || (cv == bv5[TOPK - 1] && ci < bi5[TOPK - 1])) {
                    INSERT5(bv5, bi5, cv, ci);
                }
            }
        size_t base = ((size_t)(b0 + tid) * FNCH + chunk) * TOPK;
        #pragma unroll
        for (int s = 0; s < TOPK; ++s) { cval[base + s] = bv5[s]; cidx[base + s] = bi5[s]; }
    }
}

__global__ __launch_bounds__(256)
void knn_phaseB_fb(const float* __restrict__ cval, const int* __restrict__ cidx,
                   const int* __restrict__ y, int* __restrict__ out) {
    int b = blockIdx.x * blockDim.x + threadIdx.x;
    if (b >= B_TEST) return;
    const float* v = cval + (size_t)b * FNCH * TOPK;
    const int* ix = cidx + (size_t)b * FNCH * TOPK;
    float bv5[TOPK]; int bi5[TOPK];
    #pragma unroll
    for (int s = 0; s < TOPK; ++s) { bv5[s] = -FLT_MAX; bi5[s] = 0x7fffffff; }
    for (int tt = 0; tt < FNCH * TOPK; ++tt) {
        float cv = v[tt]; int ci = ix[tt];
        if (cv > bv5[TOPK - 1] || (cv == bv5[TOPK - 1] && ci < bi5[TOPK - 1])) {
            INSERT5(bv5, bi5, cv, ci);
        }
    }
    int lab[TOPK];
    #pragma unroll
    for (int s = 0; s < TOPK; ++s) lab[s] = y[bi5[s]];
    int best_c = 0, best_cnt = -1;
    #pragma unroll
    for (int cc = 0; cc < N_CLASSES; ++cc) {
        int cnt = 0;
        #pragma unroll
        for (int s = 0; s < TOPK; ++s) cnt += (lab[s] == cc) ? 1 : 0;
        if (cnt > best_cnt) { best_cnt = cnt; best_c = cc; }
    }
    out[b] = best_c;
}

// =====================================================================
extern "C" void kernel_launch(void* const* d_in, const int* in_sizes, int n_in,
                              void* d_out, int out_size, void* d_ws, size_t ws_size,
                              hipStream_t stream) {
    const float* x_test  = (const float*)d_in[0];
    const float* x_train = (const float*)d_in[1];
    const int*   y_train = (const int*)d_in[2];
    int* out = (int*)d_out;

    // fast-path workspace layout (bytes)
    const size_t sz_Bq  = (size_t)NPAD * KPADB;            // 41,639,936
    const size_t off_Aq = sz_Bq;
    const size_t sz_Aq  = (size_t)B_TEST * KPADB;          // 1,703,936
    const size_t off_cv = off_Aq + sz_Aq;
    const size_t sz_cv  = (size_t)B_TEST * NBLK * TOPK * 4;  // 16,015,360
    const size_t need   = off_cv + sz_cv;                  // ~59.4 MB

    char* ws = (char*)d_ws;

    if (ws_size >= need) {
        char* Bq = ws;
        char* Aq = ws + off_Aq;
        unsigned* cval = (unsigned*)(ws + off_cv);

        quant_kernel<<<NPAD / 4 + B_TEST / 4, 256, 0, stream>>>(
            x_train, x_test, Bq, Aq);

        knn_mfma<<<6272, 256, 0, stream>>>(Aq, Bq, cval);

        knn_final<<<B_TEST, 256, 0, stream>>>(cval, x_test, x_train, y_train, out);
    } else {
        float* strain = (float*)ws;
        rowsum_kernel<<<N_TRAIN / 4, 256, 0, stream>>>(x_train, strain);
        float* cval = (float*)(ws + 200192);
        int*   cidx = (int*)(ws + 200192 + (size_t)B_TEST * FNCH * TOPK * 4);

        dim3 gridA(B_TEST / FBM, FNCH);
        knn_phaseA_fb<<<gridA, 256, 0, stream>>>(x_test, x_train, strain, cval, cidx);
        knn_phaseB_fb<<<(B_TEST + 255) / 256, 256, 0, stream>>>(cval, cidx, y_train, out);
    }
}

// Round 4
// 430.297 us; speedup vs baseline: 1.2510x; 1.2510x over previous
//
#include <hip/hip_runtime.h>
#include <float.h>
#include <stdint.h>

#define D_DIM 784
#define KPADB 896           // 7 x 128 bytes (i8 per row, zero-padded)
#define N_TRAIN 50000
#define NPAD 50048
#define B_TEST 2048
#define N_CLASSES 10
#define TOPK 5
#define NBLK 391            // ceil(50048/128)
#define SEL 8               // exact-rescore candidate count per row
#define SBIAS 12645136      // 784 * 127^2: makes integer score non-negative

typedef __attribute__((ext_vector_type(4))) int int4v;

__device__ inline unsigned umax32(unsigned a, unsigned b) { return a > b ? a : b; }

// branchless sorted-insert (desc) of u64 into 8-deep list
__device__ inline void ins8(unsigned long long* tk, unsigned long long v) {
    #pragma unroll
    for (int s = 0; s < SEL; ++s) {
        unsigned long long mx = v > tk[s] ? v : tk[s];
        unsigned long long mn = v > tk[s] ? tk[s] : v;
        tk[s] = mx; v = mn;
    }
}

// branchless sorted-insert (desc) of u32 into 5-deep list
__device__ inline void ins5u(unsigned* tk, unsigned v) {
    #pragma unroll
    for (int s = 0; s < TOPK; ++s) {
        unsigned mx = v > tk[s] ? v : tk[s];
        unsigned mn = v > tk[s] ? tk[s] : v;
        tk[s] = mx; v = mn;
    }
}

// float pair-insert for fallback path
#define INSERT5(tvarr, tiarr, CV, CI)                                   \
    {                                                                   \
        float _cv = (CV); int _ci = (CI);                               \
        _Pragma("unroll")                                               \
        for (int _s = 0; _s < TOPK; ++_s) {                             \
            bool _bet = (_cv > tvarr[_s]) ||                            \
                        (_cv == tvarr[_s] && _ci < tiarr[_s]);          \
            float _fv = _bet ? tvarr[_s] : _cv;                         \
            int   _fi = _bet ? tiarr[_s] : _ci;                         \
            tvarr[_s] = _bet ? _cv : tvarr[_s];                         \
            tiarr[_s] = _bet ? _ci : tiarr[_s];                         \
            _cv = _fv; _ci = _fi;                                       \
        }                                                               \
    }

// pack 4 floats -> 4 x i8 (q = round(254*x - 127), symmetric centered quant)
__device__ inline unsigned pack4q(float4 f) {
    int q0 = __float2int_rn(fmaf(f.x, 254.f, -127.f));
    int q1 = __float2int_rn(fmaf(f.y, 254.f, -127.f));
    int q2 = __float2int_rn(fmaf(f.z, 254.f, -127.f));
    int q3 = __float2int_rn(fmaf(f.w, 254.f, -127.f));
    return (unsigned)(q0 & 255) | ((unsigned)(q1 & 255) << 8) |
           ((unsigned)(q2 & 255) << 16) | ((unsigned)(q3 & 255) << 24);
}

// ---------- quantize fp32 -> i8 (centered), both tensors, one launch ----------
// one wave per row; lane covers 16 elements (16 bytes out). Pad bytes = 0
// (q=0 means u=0 -> contributes nothing to the centered dot product).
__global__ __launch_bounds__(256)
void quant_kernel(const float* __restrict__ xtr, const float* __restrict__ xte,
                  char* __restrict__ Bq, char* __restrict__ Aq) {
    const int blk = blockIdx.x;
    const float* src;
    char* dst;
    int rows_src, row;
    if (blk < NPAD / 4) {
        src = xtr; dst = Bq; rows_src = N_TRAIN;
        row = blk * 4 + (threadIdx.x >> 6);
    } else {
        src = xte; dst = Aq; rows_src = B_TEST;
        row = (blk - NPAD / 4) * 4 + (threadIdx.x >> 6);
        if (row >= B_TEST) return;
    }
    const int lane = threadIdx.x & 63;
    if (lane >= 56) return;                       // 56*16 = 896 bytes per row
    uint4 w = {0u, 0u, 0u, 0u};
    if (row < rows_src && lane < 49) {            // 49*16 = 784 real elements
        const float4* p = (const float4*)(src + (size_t)row * D_DIM + lane * 16);
        w.x = pack4q(p[0]);
        w.y = pack4q(p[1]);
        w.z = pack4q(p[2]);
        w.w = pack4q(p[3]);
    }
    *(uint4*)(dst + (size_t)row * KPADB + lane * 16) = w;
}

// ---------------- i8 MFMA GEMM + packed-u32 top-5 epilogue ----------------
// BK=128 bytes: per K-tile 8 G2L/thread, 16 ds_read_b128/wave, 32 MFMA/wave,
// 2 barriers -> 7 iterations total. LDS staging geometry (64 rows x 128 B,
// 8-chunk XOR swizzle) is identical to the verified round-2 f16 kernel.
// Score = sum(qa*qb) is the exact integer rank key (rowsum cancels for centered
// quant); key = ((s + SBIAS) << 7) | col is lossless (25+7 = 32 bits).
// launch_bounds(256,3): occupancy is LDS-bound at 3 blocks/CU anyway (r2/r3
// both measured ~40%); the looser reg budget (~170) avoids epilogue spill
// (r3's (256,4) build showed WRITE_SIZE 96.7 MB vs 21.7 expected -> scratch).
__global__ __launch_bounds__(256, 3)
void knn_mfma(const char* __restrict__ Aq, const char* __restrict__ Bq,
              unsigned* __restrict__ cval) {
    const int bid = blockIdx.x;
    const int xcd = bid & 7;
    const int sidx = bid >> 3;
    const int st_g = (sidx >> 4) * 8 + xcd;
    const int r16 = sidx & 15;
    const int mblk = (st_g & 3) * 4 + (r16 & 3);
    const int nchunk = (st_g >> 2) * 4 + (r16 >> 2);
    if (nchunk >= NBLK) return;

    __shared__ char lds_raw[39936] __attribute__((aligned(16)));
    // staging: A tile 16KB at +0, B tile 16KB at +16384 (32 KB of 39936)
    unsigned* epi  = (unsigned*)lds_raw;             // [128 cols][68] u32
    unsigned* lval = (unsigned*)(lds_raw + 34816);   // [64][4][5] u32

    const int tid = threadIdx.x;
    const int w = tid >> 6, lane = tid & 63;
    const int l15 = lane & 15, q = lane >> 4;
    const int mb = mblk * 128, nb = nchunk * 128;
    const int mw = (w & 1) * 64, nw = (w >> 1) * 64;

    // staging: wave w loads half-tile: tile = w>>1 (0=A,1=B), half = w&1
    const int s_tile = w >> 1, s_half = w & 1;
    const char* sbase = (s_tile == 0) ? (Aq + (size_t)mb * KPADB)
                                      : (Bq + (size_t)nb * KPADB);
    const char* srow = sbase + (size_t)s_half * 64 * KPADB;
    char* ldsw = lds_raw + s_tile * 16384 + s_half * 8192;

    // pre-swizzled global source offsets (8 chunks of 16B per 128B row-tile)
    int choff[8];
    #pragma unroll
    for (int c = 0; c < 8; ++c) {
        int s = c * 64 + lane;               // 16B-chunk index in half-tile
        int rl = s >> 3;                     // row-in-half 0..63
        int k8 = (s & 7) ^ (rl & 7);         // swizzled chunk (8-wide XOR)
        choff[c] = rl * KPADB + k8 * 16;
    }
    // swizzled ds_read byte offsets; row&7 == l15&7 for all fragment rows
    int aoff[4][2], boff[4][2];
    #pragma unroll
    for (int k64 = 0; k64 < 2; ++k64) {
        int ch = ((k64 * 4 + q) ^ (l15 & 7)) * 16;
        #pragma unroll
        for (int i = 0; i < 4; ++i) {
            aoff[i][k64] = (mw + i * 16 + l15) * 128 + ch;
            boff[i][k64] = (nw + i * 16 + l15) * 128 + ch;
        }
    }

    int4v acc[4][4];
    #pragma unroll
    for (int i = 0; i < 4; ++i)
        #pragma unroll
        for (int j = 0; j < 4; ++j)
            acc[i][j] = (int4v){0, 0, 0, 0};

    for (int kt = 0; kt < KPADB; kt += 128) {
        #pragma unroll
        for (int c = 0; c < 8; ++c) {
            __builtin_amdgcn_global_load_lds(
                (const __attribute__((address_space(1))) void*)(srow + choff[c] + kt),
                (__attribute__((address_space(3))) void*)(ldsw + c * 1024),
                16, 0, 0);
        }
        __syncthreads();
        #pragma unroll
        for (int k64 = 0; k64 < 2; ++k64) {
            int4v a[4], b[4];
            #pragma unroll
            for (int i = 0; i < 4; ++i) a[i] = *(const int4v*)(lds_raw + aoff[i][k64]);
            #pragma unroll
            for (int j = 0; j < 4; ++j) b[j] = *(const int4v*)(lds_raw + 16384 + boff[j][k64]);
            #pragma unroll
            for (int i = 0; i < 4; ++i)
                #pragma unroll
                for (int j = 0; j < 4; ++j)
                    acc[i][j] = __builtin_amdgcn_mfma_i32_16x16x64_i8(a[i], b[j], acc[i][j], 0, 0, 0);
        }
        __syncthreads();
    }

    // ---- epilogue: packed keys + branch-free top-5 per (row, chunk) ----
    int okn[4];
    #pragma unroll
    for (int j = 0; j < 4; ++j) okn[j] = (nb + nw + j * 16 + l15 < N_TRAIN);

    for (int h = 0; h < 2; ++h) {
        __syncthreads();
        if ((w & 1) == h) {
            #pragma unroll
            for (int i = 0; i < 4; ++i) {
                int r = i * 16 + q * 4;
                #pragma unroll
                for (int j = 0; j < 4; ++j) {
                    int col = nw + j * 16 + l15;
                    uint4 kv;
                    if (okn[j]) {
                        int4v s = acc[i][j];
                        kv.x = ((unsigned)(s.x + SBIAS) << 7) | (unsigned)col;
                        kv.y = ((unsigned)(s.y + SBIAS) << 7) | (unsigned)col;
                        kv.z = ((unsigned)(s.z + SBIAS) << 7) | (unsigned)col;
                        kv.w = ((unsigned)(s.w + SBIAS) << 7) | (unsigned)col;
                    } else {
                        kv.x = kv.y = kv.z = kv.w = (unsigned)col;
                    }
                    *(uint4*)(epi + col * 68 + r) = kv;
                }
            }
        }
        __syncthreads();
        // scan: thread t -> row (t&63), col-quarter (t>>6); branch-free extraction
        {
            int r = tid & 63, qq = tid >> 6;
            const unsigned* ebase = epi + (qq * 32) * 68 + r;
            unsigned k[32];
            #pragma unroll
            for (int c = 0; c < 32; ++c) k[c] = ebase[c * 68];
            unsigned m5[TOPK];
            #pragma unroll
            for (int rnd = 0; rnd < TOPK; ++rnd) {
                unsigned t16[16];
                #pragma unroll
                for (int c = 0; c < 16; ++c) t16[c] = umax32(k[2*c], k[2*c+1]);
                #pragma unroll
                for (int c = 0; c < 8; ++c) t16[c] = umax32(t16[2*c], t16[2*c+1]);
                #pragma unroll
                for (int c = 0; c < 4; ++c) t16[c] = umax32(t16[2*c], t16[2*c+1]);
                unsigned m = umax32(umax32(t16[0], t16[1]), umax32(t16[2], t16[3]));
                m5[rnd] = m;
                if (rnd < TOPK - 1) {
                    #pragma unroll
                    for (int c = 0; c < 32; ++c) k[c] = (k[c] == m) ? 0u : k[c];
                }
            }
            #pragma unroll
            for (int s = 0; s < TOPK; ++s) lval[(r * 4 + qq) * TOPK + s] = m5[s];
        }
        __syncthreads();
        if (tid < 64) {
            unsigned tv[TOPK] = {0u, 0u, 0u, 0u, 0u};
            for (int qq = 0; qq < 4; ++qq)
                #pragma unroll
                for (int s = 0; s < TOPK; ++s) {
                    unsigned cv = lval[(tid * 4 + qq) * TOPK + s];
                    if (cv > tv[TOPK - 1]) ins5u(tv, cv);
                }
            int grow = mb + h * 64 + tid;
            size_t base = ((size_t)grow * NBLK + nchunk) * TOPK;
            #pragma unroll
            for (int s = 0; s < TOPK; ++s) cval[base + s] = tv[s];
        }
    }
}

// ------- merge packed candidates -> top-8, exact fp64 rescore, vote -------
__global__ __launch_bounds__(256)
void knn_final(const unsigned* __restrict__ cval,
               const float* __restrict__ xt, const float* __restrict__ xtr,
               const int* __restrict__ y, int* __restrict__ out) {
    __shared__ unsigned long long sv[256][SEL];   // 16 KB
    __shared__ double cs[SEL];
    __shared__ int    cn[SEL];
    const int b = blockIdx.x;
    const int t = threadIdx.x;

    unsigned long long tk[SEL];
    #pragma unroll
    for (int s = 0; s < SEL; ++s) tk[s] = 0ull;

    const unsigned* row = cval + (size_t)b * (NBLK * TOPK);
    for (int e = t; e < NBLK * TOPK; e += 256) {
        unsigned v = row[e];
        int chunk = e / TOPK;                       // magic-mul
        unsigned n = (unsigned)chunk * 128u + (v & 127u);
        unsigned long long v64 = ((unsigned long long)v << 16) | n;
        if (v64 > tk[SEL - 1]) ins8(tk, v64);
    }
    #pragma unroll
    for (int s = 0; s < SEL; ++s) sv[t][s] = tk[s];
    __syncthreads();

    for (int off = 128; off >= 1; off >>= 1) {
        if (t < off) {
            if (sv[t + off][0] > tk[SEL - 1]) {
                #pragma unroll
                for (int s = 0; s < SEL; ++s) {
                    unsigned long long v = sv[t + off][s];
                    if (v > tk[SEL - 1]) ins8(tk, v);
                }
                #pragma unroll
                for (int s = 0; s < SEL; ++s) sv[t][s] = tk[s];
            }
        }
        __syncthreads();
    }

    // exact fp64 rescore: candidate c handled by half-wave (w*2 + half)
    const int w = t >> 6, lane = t & 63, half = lane >> 5, hl = lane & 31;
    const int c = w * 2 + half;
    {
        int n = (int)(sv[0][c] & 0xFFFFull);
        double dot = 0.0, rs = 0.0;
        if (n < N_TRAIN) {
            const float4* pa = (const float4*)(xt + (size_t)b * D_DIM);
            const float4* pb = (const float4*)(xtr + (size_t)n * D_DIM);
            #pragma unroll
            for (int jj = 0; jj < 7; ++jj) {
                int j = hl + jj * 32;
                if (j < 196) {
                    float4 a = pa[j], bb = pb[j];
                    dot += (double)a.x * bb.x + (double)a.y * bb.y +
                           (double)a.z * bb.z + (double)a.w * bb.w;
                    rs  += (double)bb.x + (double)bb.y + (double)bb.z + (double)bb.w;
                }
            }
        }
        #pragma unroll
        for (int off = 16; off > 0; off >>= 1) {
            dot += __shfl_down(dot, off, 32);
            rs  += __shfl_down(rs, off, 32);
        }
        if (hl == 0) {
            cs[c] = (n < N_TRAIN) ? (2.0 * dot - rs) : -1.0e300;
            cn[c] = n;
        }
    }
    __syncthreads();

    if (t == 0) {
        double bv[TOPK]; int bi[TOPK];
        #pragma unroll
        for (int s = 0; s < TOPK; ++s) { bv[s] = -1.0e300; bi[s] = 0x7fffffff; }
        for (int cc = 0; cc < SEL; ++cc) {
            double cv = cs[cc]; int ci = cn[cc];
            #pragma unroll
            for (int s = 0; s < TOPK; ++s) {
                bool bet = (cv > bv[s]) || (cv == bv[s] && ci < bi[s]);
                double fv = bet ? bv[s] : cv;
                int    fi = bet ? bi[s] : ci;
                bv[s] = bet ? cv : bv[s];
                bi[s] = bet ? ci : bi[s];
                cv = fv; ci = fi;
            }
        }
        int lab[TOPK];
        #pragma unroll
        for (int s = 0; s < TOPK; ++s) lab[s] = y[bi[s]];
        int best_c = 0, best_cnt = -1;
        #pragma unroll
        for (int cc = 0; cc < N_CLASSES; ++cc) {
            int cnt = 0;
            #pragma unroll
            for (int s = 0; s < TOPK; ++s) cnt += (lab[s] == cc) ? 1 : 0;
            if (cnt > best_cnt) { best_cnt = cnt; best_c = cc; }
        }
        out[b] = best_c;
    }
}

// ================= fallback (round-1 fp32 path, known-correct) =================
#define FBM 64
#define FBN 64
#define FBK 16
#define FNCH 32
#define FCHUNK 1600

__global__ __launch_bounds__(256)
void rowsum_kernel(const float* __restrict__ x, float* __restrict__ s) {
    int row = blockIdx.x * 4 + (threadIdx.x >> 6);
    int lane = threadIdx.x & 63;
    if (row >= N_TRAIN) return;
    const float* p = x + (size_t)row * D_DIM;
    float acc = 0.f;
    for (int i = lane; i < D_DIM; i += 64) acc += p[i];
    #pragma unroll
    for (int off = 32; off > 0; off >>= 1) acc += __shfl_down(acc, off, 64);
    if (lane == 0) s[row] = acc;
}

__global__ __launch_bounds__(256)
void knn_phaseA_fb(const float* __restrict__ xt, const float* __restrict__ xtr,
                   const float* __restrict__ strain,
                   float* __restrict__ cval, int* __restrict__ cidx) {
    __shared__ float As[FBK][FBM + 4];
    __shared__ float Bs[FBK][FBN + 4];
    __shared__ float lv[FBM][16][TOPK];
    __shared__ int   li[FBM][16][TOPK];

    const int tid = threadIdx.x;
    const int tx = tid & 15, ty = tid >> 4;
    const int b0 = blockIdx.x * FBM;
    const int chunk = blockIdx.y;
    const int n_base = chunk * FCHUNK;
    const int lrow = tid >> 2;
    const int lk4  = (tid & 3) * 4;

    float tv[4][TOPK]; int ti[4][TOPK];
    #pragma unroll
    for (int i = 0; i < 4; ++i)
        #pragma unroll
        for (int s = 0; s < TOPK; ++s) { tv[i][s] = -FLT_MAX; ti[i][s] = 0x7fffffff; }

    for (int nt = 0; nt < FCHUNK; nt += FBN) {
        const int n0 = n_base + nt;
        double accd[4][4];
        #pragma unroll
        for (int i = 0; i < 4; ++i)
            #pragma unroll
            for (int j = 0; j < 4; ++j) accd[i][j] = 0.0;

        for (int kt = 0; kt < D_DIM; kt += FBK) {
            float4 av = *(const float4*)(xt + (size_t)(b0 + lrow) * D_DIM + kt + lk4);
            As[lk4 + 0][lrow] = av.x; As[lk4 + 1][lrow] = av.y;
            As[lk4 + 2][lrow] = av.z; As[lk4 + 3][lrow] = av.w;
            int nr = n0 + lrow;
            float4 bv = make_float4(0.f, 0.f, 0.f, 0.f);
            if (nr < N_TRAIN) bv = *(const float4*)(xtr + (size_t)nr * D_DIM + kt + lk4);
            Bs[lk4 + 0][lrow] = bv.x; Bs[lk4 + 1][lrow] = bv.y;
            Bs[lk4 + 2][lrow] = bv.z; Bs[lk4 + 3][lrow] = bv.w;
            __syncthreads();

            float accf[4][4] = {{0.f}};
            #pragma unroll
            for (int k = 0; k < FBK; ++k) {
                float a[4], b[4];
                #pragma unroll
                for (int i = 0; i < 4; ++i) a[i] = As[k][ty * 4 + i];
                #pragma unroll
                for (int j = 0; j < 4; ++j) b[j] = Bs[k][tx * 4 + j];
                #pragma unroll
                for (int i = 0; i < 4; ++i)
                    #pragma unroll
                    for (int j = 0; j < 4; ++j) accf[i][j] += a[i] * b[j];
            }
            #pragma unroll
            for (int i = 0; i < 4; ++i)
                #pragma unroll
                for (int j = 0; j < 4; ++j) accd[i][j] += (double)accf[i][j];
            __syncthreads();
        }

        #pragma unroll
        for (int j = 0; j < 4; ++j) {
            int n = n0 + tx * 4 + j;
            if (n < N_TRAIN) {
                float sn = strain[n];
                #pragma unroll
                for (int i = 0; i < 4; ++i) {
                    float sc = (float)(2.0 * accd[i][j] - (double)sn);
                    if (sc > tv[i][TOPK - 1] ||
                        (sc == tv[i][TOPK - 1] && n < ti[i][TOPK - 1])) {
                        INSERT5(tv[i], ti[i], sc, n);
                    }
                }
            }
        }
    }

    #pragma unroll
    for (int i = 0; i < 4; ++i)
        #pragma unroll
        for (int s = 0; s < TOPK; ++s) {
            lv[ty * 4 + i][tx][s] = tv[i][s];
            li[ty * 4 + i][tx][s] = ti[i][s];
        }
    __syncthreads();

    if (tid < FBM) {
        float bv5[TOPK]; int bi5[TOPK];
        #pragma unroll
        for (int s = 0; s < TOPK; ++s) { bv5[s] = -FLT_MAX; bi5[s] = 0x7fffffff; }
        for (int tt = 0; tt < 16; ++tt)
            #pragma unroll
            for (int s = 0; s < TOPK; ++s) {
                float cv = lv[tid][tt][s]; int ci = li[tid][tt][s];
                if (cv > bv5[TOPK - 1] || (cv == bv5[TOPK - 1] && ci < bi5[TOPK - 1])) {
                    INSERT5(bv5, bi5, cv, ci);
                }
            }
        size_t base = ((size_t)(b0 + tid) * FNCH + chunk) * TOPK;
        #pragma unroll
        for (int s = 0; s < TOPK; ++s) { cval[base + s] = bv5[s]; cidx[base + s] = bi5[s]; }
    }
}

__global__ __launch_bounds__(256)
void knn_phaseB_fb(const float* __restrict__ cval, const int* __restrict__ cidx,
                   const int* __restrict__ y, int* __restrict__ out) {
    int b = blockIdx.x * blockDim.x + threadIdx.x;
    if (b >= B_TEST) return;
    const float* v = cval + (size_t)b * FNCH * TOPK;
    const int* ix = cidx + (size_t)b * FNCH * TOPK;
    float bv5[TOPK]; int bi5[TOPK];
    #pragma unroll
    for (int s = 0; s < TOPK; ++s) { bv5[s] = -FLT_MAX; bi5[s] = 0x7fffffff; }
    for (int tt = 0; tt < FNCH * TOPK; ++tt) {
        float cv = v[tt]; int ci = ix[tt];
        if (cv > bv5[TOPK - 1] || (cv == bv5[TOPK - 1] && ci < bi5[TOPK - 1])) {
            INSERT5(bv5, bi5, cv, ci);
        }
    }
    int lab[TOPK];
    #pragma unroll
    for (int s = 0; s < TOPK; ++s) lab[s] = y[bi5[s]];
    int best_c = 0, best_cnt = -1;
    #pragma unroll
    for (int cc = 0; cc < N_CLASSES; ++cc) {
        int cnt = 0;
        #pragma unroll
        for (int s = 0; s < TOPK; ++s) cnt += (lab[s] == cc) ? 1 : 0;
        if (cnt > best_cnt) { best_cnt = cnt; best_c = cc; }
    }
    out[b] = best_c;
}

// =====================================================================
extern "C" void kernel_launch(void* const* d_in, const int* in_sizes, int n_in,
                              void* d_out, int out_size, void* d_ws, size_t ws_size,
                              hipStream_t stream) {
    const float* x_test  = (const float*)d_in[0];
    const float* x_train = (const float*)d_in[1];
    const int*   y_train = (const int*)d_in[2];
    int* out = (int*)d_out;

    // fast-path workspace layout (bytes)
    const size_t sz_Bq  = (size_t)NPAD * KPADB;            // 44,843,008
    const size_t off_Aq = sz_Bq;
    const size_t sz_Aq  = (size_t)B_TEST * KPADB;          // 1,835,008
    const size_t off_cv = off_Aq + sz_Aq;
    const size_t sz_cv  = (size_t)B_TEST * NBLK * TOPK * 4;  // 16,015,360
    const size_t need   = off_cv + sz_cv;                  // ~62.7 MB

    char* ws = (char*)d_ws;

    if (ws_size >= need) {
        char* Bq = ws;
        char* Aq = ws + off_Aq;
        unsigned* cval = (unsigned*)(ws + off_cv);

        quant_kernel<<<NPAD / 4 + B_TEST / 4, 256, 0, stream>>>(
            x_train, x_test, Bq, Aq);

        knn_mfma<<<6272, 256, 0, stream>>>(Aq, Bq, cval);

        knn_final<<<B_TEST, 256, 0, stream>>>(cval, x_test, x_train, y_train, out);
    } else {
        float* strain = (float*)ws;
        rowsum_kernel<<<N_TRAIN / 4, 256, 0, stream>>>(x_train, strain);
        float* cval = (float*)(ws + 200192);
        int*   cidx = (int*)(ws + 200192 + (size_t)B_TEST * FNCH * TOPK * 4);

        dim3 gridA(B_TEST / FBM, FNCH);
        knn_phaseA_fb<<<gridA, 256, 0, stream>>>(x_test, x_train, strain, cval, cidx);
        knn_phaseB_fb<<<(B_TEST + 255) / 256, 256, 0, stream>>>(cval, cidx, y_train, out);
    }
}

// Round 5
// 384.329 us; speedup vs baseline: 1.4006x; 1.1196x over previous
//
#include <hip/hip_runtime.h>
#include <float.h>
#include <stdint.h>

#define D_DIM 784
#define KPADB 896           // 7 x 128 bytes (i8 per row, zero-padded)
#define N_TRAIN 50000
#define NPAD 50048
#define B_TEST 2048
#define N_CLASSES 10
#define TOPK 5
#define NBLK 391            // ceil(50048/128)
#define SEL 8               // exact-rescore candidate count per row
#define SBIAS 12645136      // 784 * 127^2: makes integer score non-negative

typedef __attribute__((ext_vector_type(4))) int int4v;

__device__ inline unsigned umax32(unsigned a, unsigned b) { return a > b ? a : b; }

// branchless sorted-insert (desc) of u64 into 8-deep list
__device__ inline void ins8(unsigned long long* tk, unsigned long long v) {
    #pragma unroll
    for (int s = 0; s < SEL; ++s) {
        unsigned long long mx = v > tk[s] ? v : tk[s];
        unsigned long long mn = v > tk[s] ? tk[s] : v;
        tk[s] = mx; v = mn;
    }
}

// branchless sorted-insert (desc) of u32 into 5-deep list
__device__ inline void ins5u(unsigned* tk, unsigned v) {
    #pragma unroll
    for (int s = 0; s < TOPK; ++s) {
        unsigned mx = v > tk[s] ? v : tk[s];
        unsigned mn = v > tk[s] ? tk[s] : v;
        tk[s] = mx; v = mn;
    }
}

// float pair-insert for fallback path
#define INSERT5(tvarr, tiarr, CV, CI)                                   \
    {                                                                   \
        float _cv = (CV); int _ci = (CI);                               \
        _Pragma("unroll")                                               \
        for (int _s = 0; _s < TOPK; ++_s) {                             \
            bool _bet = (_cv > tvarr[_s]) ||                            \
                        (_cv == tvarr[_s] && _ci < tiarr[_s]);          \
            float _fv = _bet ? tvarr[_s] : _cv;                         \
            int   _fi = _bet ? tiarr[_s] : _ci;                         \
            tvarr[_s] = _bet ? _cv : tvarr[_s];                         \
            tiarr[_s] = _bet ? _ci : tiarr[_s];                         \
            _cv = _fv; _ci = _fi;                                       \
        }                                                               \
    }

// pack 4 floats -> 4 x i8 (q = round(254*x - 127), symmetric centered quant)
__device__ inline unsigned pack4q(float4 f) {
    int q0 = __float2int_rn(fmaf(f.x, 254.f, -127.f));
    int q1 = __float2int_rn(fmaf(f.y, 254.f, -127.f));
    int q2 = __float2int_rn(fmaf(f.z, 254.f, -127.f));
    int q3 = __float2int_rn(fmaf(f.w, 254.f, -127.f));
    return (unsigned)(q0 & 255) | ((unsigned)(q1 & 255) << 8) |
           ((unsigned)(q2 & 255) << 16) | ((unsigned)(q3 & 255) << 24);
}

// ---------- quantize fp32 -> i8 (centered), both tensors, one launch ----------
// one wave per row; lane covers 16 elements (16 bytes out). Pad bytes = 0
// (q=0 means u=0 -> contributes nothing to the centered dot product).
__global__ __launch_bounds__(256)
void quant_kernel(const float* __restrict__ xtr, const float* __restrict__ xte,
                  char* __restrict__ Bq, char* __restrict__ Aq) {
    const int blk = blockIdx.x;
    const float* src;
    char* dst;
    int rows_src, row;
    if (blk < NPAD / 4) {
        src = xtr; dst = Bq; rows_src = N_TRAIN;
        row = blk * 4 + (threadIdx.x >> 6);
    } else {
        src = xte; dst = Aq; rows_src = B_TEST;
        row = (blk - NPAD / 4) * 4 + (threadIdx.x >> 6);
        if (row >= B_TEST) return;
    }
    const int lane = threadIdx.x & 63;
    if (lane >= 56) return;                       // 56*16 = 896 bytes per row
    uint4 w = {0u, 0u, 0u, 0u};
    if (row < rows_src && lane < 49) {            // 49*16 = 784 real elements
        const float4* p = (const float4*)(src + (size_t)row * D_DIM + lane * 16);
        w.x = pack4q(p[0]);
        w.y = pack4q(p[1]);
        w.z = pack4q(p[2]);
        w.w = pack4q(p[3]);
    }
    *(uint4*)(dst + (size_t)row * KPADB + lane * 16) = w;
}

// ---------------- i8 MFMA GEMM + packed-u32 top-5 epilogue ----------------
// BK=128 bytes: per K-tile 8 G2L/thread, 16 ds_read_b128/wave, 32 MFMA/wave,
// 2 barriers -> 7 iterations total. LDS staging geometry (64 rows x 128 B,
// 8-chunk XOR swizzle) is identical to the verified round-2 f16 kernel.
// Score = sum(qa*qb) is the exact integer rank key (rowsum cancels for centered
// quant); key = ((s + SBIAS) << 7) | col is lossless (25+7 = 32 bits).
// launch_bounds(256,4): 4 blocks/CU (LDS 4x39936 = 159.7 KB fits exactly).
// The r4 build missed the 4th block because the tree-scan epilogue needed
// 84 arch VGPR (+64 acc) > 128/wave; the streaming ins5u scan below keeps
// epilogue live-regs ~12 so the whole wave fits the 128-reg budget.
__global__ __launch_bounds__(256, 4)
void knn_mfma(const char* __restrict__ Aq, const char* __restrict__ Bq,
              unsigned* __restrict__ cval) {
    const int bid = blockIdx.x;
    const int xcd = bid & 7;
    const int sidx = bid >> 3;
    const int st_g = (sidx >> 4) * 8 + xcd;
    const int r16 = sidx & 15;
    const int mblk = (st_g & 3) * 4 + (r16 & 3);
    const int nchunk = (st_g >> 2) * 4 + (r16 >> 2);
    if (nchunk >= NBLK) return;

    __shared__ char lds_raw[39936] __attribute__((aligned(16)));
    // staging: A tile 16KB at +0, B tile 16KB at +16384 (32 KB of 39936)
    unsigned* epi  = (unsigned*)lds_raw;             // [128 cols][68] u32
    unsigned* lval = (unsigned*)(lds_raw + 34816);   // [64][4][5] u32

    const int tid = threadIdx.x;
    const int w = tid >> 6, lane = tid & 63;
    const int l15 = lane & 15, q = lane >> 4;
    const int mb = mblk * 128, nb = nchunk * 128;
    const int mw = (w & 1) * 64, nw = (w >> 1) * 64;

    // staging: wave w loads half-tile: tile = w>>1 (0=A,1=B), half = w&1
    const int s_tile = w >> 1, s_half = w & 1;
    const char* sbase = (s_tile == 0) ? (Aq + (size_t)mb * KPADB)
                                      : (Bq + (size_t)nb * KPADB);
    const char* srow = sbase + (size_t)s_half * 64 * KPADB;
    char* ldsw = lds_raw + s_tile * 16384 + s_half * 8192;

    // pre-swizzled global source offsets (8 chunks of 16B per 128B row-tile)
    int choff[8];
    #pragma unroll
    for (int c = 0; c < 8; ++c) {
        int s = c * 64 + lane;               // 16B-chunk index in half-tile
        int rl = s >> 3;                     // row-in-half 0..63
        int k8 = (s & 7) ^ (rl & 7);         // swizzled chunk (8-wide XOR)
        choff[c] = rl * KPADB + k8 * 16;
    }
    // swizzled ds_read byte offsets; row&7 == l15&7 for all fragment rows
    int aoff[4][2], boff[4][2];
    #pragma unroll
    for (int k64 = 0; k64 < 2; ++k64) {
        int ch = ((k64 * 4 + q) ^ (l15 & 7)) * 16;
        #pragma unroll
        for (int i = 0; i < 4; ++i) {
            aoff[i][k64] = (mw + i * 16 + l15) * 128 + ch;
            boff[i][k64] = (nw + i * 16 + l15) * 128 + ch;
        }
    }

    int4v acc[4][4];
    #pragma unroll
    for (int i = 0; i < 4; ++i)
        #pragma unroll
        for (int j = 0; j < 4; ++j)
            acc[i][j] = (int4v){0, 0, 0, 0};

    for (int kt = 0; kt < KPADB; kt += 128) {
        #pragma unroll
        for (int c = 0; c < 8; ++c) {
            __builtin_amdgcn_global_load_lds(
                (const __attribute__((address_space(1))) void*)(srow + choff[c] + kt),
                (__attribute__((address_space(3))) void*)(ldsw + c * 1024),
                16, 0, 0);
        }
        __syncthreads();
        #pragma unroll
        for (int k64 = 0; k64 < 2; ++k64) {
            int4v a[4], b[4];
            #pragma unroll
            for (int i = 0; i < 4; ++i) a[i] = *(const int4v*)(lds_raw + aoff[i][k64]);
            #pragma unroll
            for (int j = 0; j < 4; ++j) b[j] = *(const int4v*)(lds_raw + 16384 + boff[j][k64]);
            #pragma unroll
            for (int i = 0; i < 4; ++i)
                #pragma unroll
                for (int j = 0; j < 4; ++j)
                    acc[i][j] = __builtin_amdgcn_mfma_i32_16x16x64_i8(a[i], b[j], acc[i][j], 0, 0, 0);
        }
        __syncthreads();
    }

    // ---- epilogue: packed keys + streaming top-5 per (row, chunk) ----
    int okn[4];
    #pragma unroll
    for (int j = 0; j < 4; ++j) okn[j] = (nb + nw + j * 16 + l15 < N_TRAIN);

    for (int h = 0; h < 2; ++h) {
        __syncthreads();
        if ((w & 1) == h) {
            #pragma unroll
            for (int i = 0; i < 4; ++i) {
                int r = i * 16 + q * 4;
                #pragma unroll
                for (int j = 0; j < 4; ++j) {
                    int col = nw + j * 16 + l15;
                    uint4 kv;
                    if (okn[j]) {
                        int4v s = acc[i][j];
                        kv.x = ((unsigned)(s.x + SBIAS) << 7) | (unsigned)col;
                        kv.y = ((unsigned)(s.y + SBIAS) << 7) | (unsigned)col;
                        kv.z = ((unsigned)(s.z + SBIAS) << 7) | (unsigned)col;
                        kv.w = ((unsigned)(s.w + SBIAS) << 7) | (unsigned)col;
                    } else {
                        kv.x = kv.y = kv.z = kv.w = (unsigned)col;
                    }
                    *(uint4*)(epi + col * 68 + r) = kv;
                }
            }
        }
        __syncthreads();
        // scan: thread t -> row (t&63), col-quarter (t>>6)
        // streaming 5-deep branchless insert: ~12 live regs (vs 48 for the
        // round-4 tree scan) so the wave fits 128 regs -> 4 blocks/CU.
        {
            int r = tid & 63, qq = tid >> 6;
            const unsigned* ebase = epi + (qq * 32) * 68 + r;
            unsigned tv5[TOPK] = {0u, 0u, 0u, 0u, 0u};
            #pragma unroll
            for (int c = 0; c < 32; ++c) ins5u(tv5, ebase[c * 68]);
            #pragma unroll
            for (int s = 0; s < TOPK; ++s) lval[(r * 4 + qq) * TOPK + s] = tv5[s];
        }
        __syncthreads();
        if (tid < 64) {
            unsigned tv[TOPK] = {0u, 0u, 0u, 0u, 0u};
            for (int qq = 0; qq < 4; ++qq)
                #pragma unroll
                for (int s = 0; s < TOPK; ++s) {
                    unsigned cv = lval[(tid * 4 + qq) * TOPK + s];
                    if (cv > tv[TOPK - 1]) ins5u(tv, cv);
                }
            int grow = mb + h * 64 + tid;
            size_t base = ((size_t)grow * NBLK + nchunk) * TOPK;
            #pragma unroll
            for (int s = 0; s < TOPK; ++s) cval[base + s] = tv[s];
        }
    }
}

// ------- merge packed candidates -> top-8, exact fp64 rescore, vote -------
__global__ __launch_bounds__(256)
void knn_final(const unsigned* __restrict__ cval,
               const float* __restrict__ xt, const float* __restrict__ xtr,
               const int* __restrict__ y, int* __restrict__ out) {
    __shared__ unsigned long long sv[256][SEL];   // 16 KB
    __shared__ double cs[SEL];
    __shared__ int    cn[SEL];
    const int b = blockIdx.x;
    const int t = threadIdx.x;

    unsigned long long tk[SEL];
    #pragma unroll
    for (int s = 0; s < SEL; ++s) tk[s] = 0ull;

    const unsigned* row = cval + (size_t)b * (NBLK * TOPK);
    for (int e = t; e < NBLK * TOPK; e += 256) {
        unsigned v = row[e];
        int chunk = e / TOPK;                       // magic-mul
        unsigned n = (unsigned)chunk * 128u + (v & 127u);
        unsigned long long v64 = ((unsigned long long)v << 16) | n;
        if (v64 > tk[SEL - 1]) ins8(tk, v64);
    }
    #pragma unroll
    for (int s = 0; s < SEL; ++s) sv[t][s] = tk[s];
    __syncthreads();

    for (int off = 128; off >= 1; off >>= 1) {
        if (t < off) {
            if (sv[t + off][0] > tk[SEL - 1]) {
                #pragma unroll
                for (int s = 0; s < SEL; ++s) {
                    unsigned long long v = sv[t + off][s];
                    if (v > tk[SEL - 1]) ins8(tk, v);
                }
                #pragma unroll
                for (int s = 0; s < SEL; ++s) sv[t][s] = tk[s];
            }
        }
        __syncthreads();
    }

    // exact fp64 rescore: candidate c handled by half-wave (w*2 + half)
    const int w = t >> 6, lane = t & 63, half = lane >> 5, hl = lane & 31;
    const int c = w * 2 + half;
    {
        int n = (int)(sv[0][c] & 0xFFFFull);
        double dot = 0.0, rs = 0.0;
        if (n < N_TRAIN) {
            const float4* pa = (const float4*)(xt + (size_t)b * D_DIM);
            const float4* pb = (const float4*)(xtr + (size_t)n * D_DIM);
            #pragma unroll
            for (int jj = 0; jj < 7; ++jj) {
                int j = hl + jj * 32;
                if (j < 196) {
                    float4 a = pa[j], bb = pb[j];
                    dot += (double)a.x * bb.x + (double)a.y * bb.y +
                           (double)a.z * bb.z + (double)a.w * bb.w;
                    rs  += (double)bb.x + (double)bb.y + (double)bb.z + (double)bb.w;
                }
            }
        }
        #pragma unroll
        for (int off = 16; off > 0; off >>= 1) {
            dot += __shfl_down(dot, off, 32);
            rs  += __shfl_down(rs, off, 32);
        }
        if (hl == 0) {
            cs[c] = (n < N_TRAIN) ? (2.0 * dot - rs) : -1.0e300;
            cn[c] = n;
        }
    }
    __syncthreads();

    if (t == 0) {
        double bv[TOPK]; int bi[TOPK];
        #pragma unroll
        for (int s = 0; s < TOPK; ++s) { bv[s] = -1.0e300; bi[s] = 0x7fffffff; }
        for (int cc = 0; cc < SEL; ++cc) {
            double cv = cs[cc]; int ci = cn[cc];
            #pragma unroll
            for (int s = 0; s < TOPK; ++s) {
                bool bet = (cv > bv[s]) || (cv == bv[s] && ci < bi[s]);
                double fv = bet ? bv[s] : cv;
                int    fi = bet ? bi[s] : ci;
                bv[s] = bet ? cv : bv[s];
                bi[s] = bet ? ci : bi[s];
                cv = fv; ci = fi;
            }
        }
        int lab[TOPK];
        #pragma unroll
        for (int s = 0; s < TOPK; ++s) lab[s] = y[bi[s]];
        int best_c = 0, best_cnt = -1;
        #pragma unroll
        for (int cc = 0; cc < N_CLASSES; ++cc) {
            int cnt = 0;
            #pragma unroll
            for (int s = 0; s < TOPK; ++s) cnt += (lab[s] == cc) ? 1 : 0;
            if (cnt > best_cnt) { best_cnt = cnt; best_c = cc; }
        }
        out[b] = best_c;
    }
}

// ================= fallback (round-1 fp32 path, known-correct) =================
#define FBM 64
#define FBN 64
#define FBK 16
#define FNCH 32
#define FCHUNK 1600

__global__ __launch_bounds__(256)
void rowsum_kernel(const float* __restrict__ x, float* __restrict__ s) {
    int row = blockIdx.x * 4 + (threadIdx.x >> 6);
    int lane = threadIdx.x & 63;
    if (row >= N_TRAIN) return;
    const float* p = x + (size_t)row * D_DIM;
    float acc = 0.f;
    for (int i = lane; i < D_DIM; i += 64) acc += p[i];
    #pragma unroll
    for (int off = 32; off > 0; off >>= 1) acc += __shfl_down(acc, off, 64);
    if (lane == 0) s[row] = acc;
}

__global__ __launch_bounds__(256)
void knn_phaseA_fb(const float* __restrict__ xt, const float* __restrict__ xtr,
                   const float* __restrict__ strain,
                   float* __restrict__ cval, int* __restrict__ cidx) {
    __shared__ float As[FBK][FBM + 4];
    __shared__ float Bs[FBK][FBN + 4];
    __shared__ float lv[FBM][16][TOPK];
    __shared__ int   li[FBM][16][TOPK];

    const int tid = threadIdx.x;
    const int tx = tid & 15, ty = tid >> 4;
    const int b0 = blockIdx.x * FBM;
    const int chunk = blockIdx.y;
    const int n_base = chunk * FCHUNK;
    const int lrow = tid >> 2;
    const int lk4  = (tid & 3) * 4;

    float tv[4][TOPK]; int ti[4][TOPK];
    #pragma unroll
    for (int i = 0; i < 4; ++i)
        #pragma unroll
        for (int s = 0; s < TOPK; ++s) { tv[i][s] = -FLT_MAX; ti[i][s] = 0x7fffffff; }

    for (int nt = 0; nt < FCHUNK; nt += FBN) {
        const int n0 = n_base + nt;
        double accd[4][4];
        #pragma unroll
        for (int i = 0; i < 4; ++i)
            #pragma unroll
            for (int j = 0; j < 4; ++j) accd[i][j] = 0.0;

        for (int kt = 0; kt < D_DIM; kt += FBK) {
            float4 av = *(const float4*)(xt + (size_t)(b0 + lrow) * D_DIM + kt + lk4);
            As[lk4 + 0][lrow] = av.x; As[lk4 + 1][lrow] = av.y;
            As[lk4 + 2][lrow] = av.z; As[lk4 + 3][lrow] = av.w;
            int nr = n0 + lrow;
            float4 bv = make_float4(0.f, 0.f, 0.f, 0.f);
            if (nr < N_TRAIN) bv = *(const float4*)(xtr + (size_t)nr * D_DIM + kt + lk4);
            Bs[lk4 + 0][lrow] = bv.x; Bs[lk4 + 1][lrow] = bv.y;
            Bs[lk4 + 2][lrow] = bv.z; Bs[lk4 + 3][lrow] = bv.w;
            __syncthreads();

            float accf[4][4] = {{0.f}};
            #pragma unroll
            for (int k = 0; k < FBK; ++k) {
                float a[4], b[4];
                #pragma unroll
                for (int i = 0; i < 4; ++i) a[i] = As[k][ty * 4 + i];
                #pragma unroll
                for (int j = 0; j < 4; ++j) b[j] = Bs[k][tx * 4 + j];
                #pragma unroll
                for (int i = 0; i < 4; ++i)
                    #pragma unroll
                    for (int j = 0; j < 4; ++j) accf[i][j] += a[i] * b[j];
            }
            #pragma unroll
            for (int i = 0; i < 4; ++i)
                #pragma unroll
                for (int j = 0; j < 4; ++j) accd[i][j] += (double)accf[i][j];
            __syncthreads();
        }

        #pragma unroll
        for (int j = 0; j < 4; ++j) {
            int n = n0 + tx * 4 + j;
            if (n < N_TRAIN) {
                float sn = strain[n];
                #pragma unroll
                for (int i = 0; i < 4; ++i) {
                    float sc = (float)(2.0 * accd[i][j] - (double)sn);
                    if (sc > tv[i][TOPK - 1] ||
                        (sc == tv[i][TOPK - 1] && n < ti[i][TOPK - 1])) {
                        INSERT5(tv[i], ti[i], sc, n);
                    }
                }
            }
        }
    }

    #pragma unroll
    for (int i = 0; i < 4; ++i)
        #pragma unroll
        for (int s = 0; s < TOPK; ++s) {
            lv[ty * 4 + i][tx][s] = tv[i][s];
            li[ty * 4 + i][tx][s] = ti[i][s];
        }
    __syncthreads();

    if (tid < FBM) {
        float bv5[TOPK]; int bi5[TOPK];
        #pragma unroll
        for (int s = 0; s < TOPK; ++s) { bv5[s] = -FLT_MAX; bi5[s] = 0x7fffffff; }
        for (int tt = 0; tt < 16; ++tt)
            #pragma unroll
            for (int s = 0; s < TOPK; ++s) {
                float cv = lv[tid][tt][s]; int ci = li[tid][tt][s];
                if (cv > bv5[TOPK - 1] || (cv == bv5[TOPK - 1] && ci < bi5[TOPK - 1])) {
                    INSERT5(bv5, bi5, cv, ci);
                }
            }
        size_t base = ((size_t)(b0 + tid) * FNCH + chunk) * TOPK;
        #pragma unroll
        for (int s = 0; s < TOPK; ++s) { cval[base + s] = bv5[s]; cidx[base + s] = bi5[s]; }
    }
}

__global__ __launch_bounds__(256)
void knn_phaseB_fb(const float* __restrict__ cval, const int* __restrict__ cidx,
                   const int* __restrict__ y, int* __restrict__ out) {
    int b = blockIdx.x * blockDim.x + threadIdx.x;
    if (b >= B_TEST) return;
    const float* v = cval + (size_t)b * FNCH * TOPK;
    const int* ix = cidx + (size_t)b * FNCH * TOPK;
    float bv5[TOPK]; int bi5[TOPK];
    #pragma unroll
    for (int s = 0; s < TOPK; ++s) { bv5[s] = -FLT_MAX; bi5[s] = 0x7fffffff; }
    for (int tt = 0; tt < FNCH * TOPK; ++tt) {
        float cv = v[tt]; int ci = ix[tt];
        if (cv > bv5[TOPK - 1] || (cv == bv5[TOPK - 1] && ci < bi5[TOPK - 1])) {
            INSERT5(bv5, bi5, cv, ci);
        }
    }
    int lab[TOPK];
    #pragma unroll
    for (int s = 0; s < TOPK; ++s) lab[s] = y[bi5[s]];
    int best_c = 0, best_cnt = -1;
    #pragma unroll
    for (int cc = 0; cc < N_CLASSES; ++cc) {
        int cnt = 0;
        #pragma unroll
        for (int s = 0; s < TOPK; ++s) cnt += (lab[s] == cc) ? 1 : 0;
        if (cnt > best_cnt) { best_cnt = cnt; best_c = cc; }
    }
    out[b] = best_c;
}

// =====================================================================
extern "C" void kernel_launch(void* const* d_in, const int* in_sizes, int n_in,
                              void* d_out, int out_size, void* d_ws, size_t ws_size,
                              hipStream_t stream) {
    const float* x_test  = (const float*)d_in[0];
    const float* x_train = (const float*)d_in[1];
    const int*   y_train = (const int*)d_in[2];
    int* out = (int*)d_out;

    // fast-path workspace layout (bytes)
    const size_t sz_Bq  = (size_t)NPAD * KPADB;            // 44,843,008
    const size_t off_Aq = sz_Bq;
    const size_t sz_Aq  = (size_t)B_TEST * KPADB;          // 1,835,008
    const size_t off_cv = off_Aq + sz_Aq;
    const size_t sz_cv  = (size_t)B_TEST * NBLK * TOPK * 4;  // 16,015,360
    const size_t need   = off_cv + sz_cv;                  // ~62.7 MB

    char* ws = (char*)d_ws;

    if (ws_size >= need) {
        char* Bq = ws;
        char* Aq = ws + off_Aq;
        unsigned* cval = (unsigned*)(ws + off_cv);

        quant_kernel<<<NPAD / 4 + B_TEST / 4, 256, 0, stream>>>(
            x_train, x_test, Bq, Aq);

        knn_mfma<<<6272, 256, 0, stream>>>(Aq, Bq, cval);

        knn_final<<<B_TEST, 256, 0, stream>>>(cval, x_test, x_train, y_train, out);
    } else {
        float* strain = (float*)ws;
        rowsum_kernel<<<N_TRAIN / 4, 256, 0, stream>>>(x_train, strain);
        float* cval = (float*)(ws + 200192);
        int*   cidx = (int*)(ws + 200192 + (size_t)B_TEST * FNCH * TOPK * 4);

        dim3 gridA(B_TEST / FBM, FNCH);
        knn_phaseA_fb<<<gridA, 256, 0, stream>>>(x_test, x_train, strain, cval, cidx);
        knn_phaseB_fb<<<(B_TEST + 255) / 256, 256, 0, stream>>>(cval, cidx, y_train, out);
    }
}